// Round 1
// baseline (811.000 us; speedup 1.0000x reference)
//
#include <hip/hip_runtime.h>

#define S_STEPS 1024
#define BATCH 128
#define NQ 8

// ---- cross-lane helpers ------------------------------------------------
template<int OFF>
__device__ __forceinline__ float swzf(float x) {
  return __int_as_float(__builtin_amdgcn_ds_swizzle(__float_as_int(x), OFF));
}
template<int CTRL>
__device__ __forceinline__ float dpp_add(float x) {
  int m = __builtin_amdgcn_update_dpp(0, __float_as_int(x), CTRL, 0xf, 0xf, true);
  return x + __int_as_float(m);
}
__device__ __forceinline__ float fast_tanh(float x) {
  x = fminf(fmaxf(x, -15.f), 15.f);
  float e = __expf(2.f * x);
  return (e - 1.f) * __builtin_amdgcn_rcpf(e + 1.f);
}

// ---- kernel 1: xw[(t*128+b)*32 + g*8+q] = bias_g[q] + x[t,b,:]·Wg[q,:256]
__global__ __launch_bounds__(256) void qlstm_pre(
    const float* __restrict__ x,
    const float* __restrict__ Wf, const float* __restrict__ bf,
    const float* __restrict__ Wi, const float* __restrict__ bi,
    const float* __restrict__ Wu, const float* __restrict__ bu,
    const float* __restrict__ Wo, const float* __restrict__ bo,
    float* __restrict__ xw)
{
  __shared__ float wsT[256][32];           // transposed: bank = col -> conflict-free
  const int tid = threadIdx.x;
  const int R0  = blockIdx.x * 64;

  for (int idx = tid; idx < 8192; idx += 256) {
    int c = idx & 31, j = idx >> 5;
    const float* Wg = (c < 8) ? Wf : (c < 16) ? Wi : (c < 24) ? Wu : Wo;
    wsT[j][c] = Wg[(c & 7) * 264 + j];
  }
  __syncthreads();

  const int c  = tid & 31;                 // output column (g*8+q)
  const int rg = tid >> 5;                 // row group, 8 rows each
  const int g  = c >> 3, q = c & 7;
  const float* bias = (g == 0) ? bf : (g == 1) ? bi : (g == 2) ? bu : bo;
  float b0 = bias[q];
  float acc[8];
#pragma unroll
  for (int k = 0; k < 8; ++k) acc[k] = b0;

  const float4* xr[8];
#pragma unroll
  for (int k = 0; k < 8; ++k)
    xr[k] = (const float4*)(x + (size_t)(R0 + rg * 8 + k) * 256);

  for (int jb = 0; jb < 64; ++jb) {
    float w0 = wsT[jb * 4 + 0][c];
    float w1 = wsT[jb * 4 + 1][c];
    float w2 = wsT[jb * 4 + 2][c];
    float w3 = wsT[jb * 4 + 3][c];
#pragma unroll
    for (int k = 0; k < 8; ++k) {
      float4 xv = xr[k][jb];               // broadcast across the 32 cols of a half-wave
      acc[k] = fmaf(xv.x, w0, acc[k]);
      acc[k] = fmaf(xv.y, w1, acc[k]);
      acc[k] = fmaf(xv.z, w2, acc[k]);
      acc[k] = fmaf(xv.w, w3, acc[k]);
    }
  }
#pragma unroll
  for (int k = 0; k < 8; ++k)
    xw[(size_t)(R0 + rg * 8 + k) * 32 + c] = acc[k];
}

// ---- kernel 2: sequential recurrence, one wave per batch element -------
// lane = g*8+i : gate g in {f,i,u,o}, prob index i (B5,B6,B7 bits of i).
// Closed-form circuit probs: p(i) ~ f0(B7) f1(B7) f5(B5) f6(B6^B5) f7(B7^B6),
// f_w = cos^2(param_w/2) or sin^2 = 1-cos^2.  RZ phases & common factor cancel.
__global__ __launch_bounds__(64) void qlstm_seq(
    const float* __restrict__ xw,
    const float* __restrict__ Wf, const float* __restrict__ Wi,
    const float* __restrict__ Wu, const float* __restrict__ Wo,
    float* __restrict__ out)
{
  const int b    = blockIdx.x;
  const int lane = threadIdx.x;
  const int g    = (lane >> 3) & 3;
  const int i    = lane & 7;
  const int B5 = (i >> 2) & 1, B6 = (i >> 1) & 1, B7 = i & 1;
  const int S0m = B7, S5m = B5, S6m = B6 ^ B5, S7m = B7 ^ B6;

  const float* Wg = (g == 0) ? Wf : (g == 1) ? Wi : (g == 2) ? Wu : Wo;
  float wh[8];
#pragma unroll
  for (int j = 0; j < 8; ++j) wh[j] = Wg[i * 264 + 256 + j];   // recurrent weights row i

  float h[8];
#pragma unroll
  for (int j = 0; j < 8; ++j) h[j] = 0.f;
  float c = 0.f, hq = 0.f;

  const float* xwp = xw + (size_t)b * 32 + lane;
  const bool ld = (lane < 32);
  float xw_cur = ld ? xwp[0]    : 0.f;     // prefetch depth 2 over the 128B/step stream
  float xw_n1  = ld ? xwp[4096] : 0.f;

  float* outp = out + (size_t)b * NQ + i;
  const bool st = (lane < 8);

#pragma unroll 1
  for (int t = 0; t < S_STEPS; ++t) {
    float xw_n2 = 0.f;
    if (ld && (t + 2 < S_STEPS)) xw_n2 = xwp[(size_t)(t + 2) * (BATCH * 32)];

    // param for (gate g, index i): x-part precomputed, add Wh·h
    float param = xw_cur;
#pragma unroll
    for (int j = 0; j < 8; ++j) param = fmaf(wh[j], h[j], param);
    float cc = fmaf(0.5f, __cosf(param), 0.5f);      // cos^2(param/2)

    // gather the 5 relevant cos^2 within own 8-lane group (q' = 0,1,5,6,7)
    float v0 = swzf<0x018>(cc);
    float v1 = swzf<0x038>(cc);
    float v5 = swzf<0x0B8>(cc);
    float v6 = swzf<0x0D8>(cc);
    float v7 = swzf<0x0F8>(cc);
    float f0 = S0m ? 1.f - v0 : v0;
    float f1 = S0m ? 1.f - v1 : v1;
    float f5 = S5m ? 1.f - v5 : v5;
    float f6 = S6m ? 1.f - v6 : v6;
    float f7 = S7m ? 1.f - v7 : v7;
    float p  = ((f0 * f1) * (f5 * f6)) * f7;

    // 8-lane sum via DPP: quad xor1, quad xor2, row_half_mirror
    float s  = dpp_add<0x141>(dpp_add<0x4E>(dpp_add<0xB1>(p)));
    float pn = p * __builtin_amdgcn_rcpf(s);

    // gather f,i,u,o for this prob index from the 4 gate groups
    float fv = swzf<0x007>(pn);
    float iv = swzf<0x107>(pn);
    float uv = swzf<0x207>(pn);
    float ov = swzf<0x307>(pn);

    float gv = fast_tanh(uv);
    c  = fmaf(fv, c, iv * gv);
    hq = ov * fast_tanh(c);

    // broadcast h[0..7] (every 8-lane group computed the full h redundantly)
    h[0] = swzf<0x018>(hq);
    h[1] = swzf<0x038>(hq);
    h[2] = swzf<0x058>(hq);
    h[3] = swzf<0x078>(hq);
    h[4] = swzf<0x098>(hq);
    h[5] = swzf<0x0B8>(hq);
    h[6] = swzf<0x0D8>(hq);
    h[7] = swzf<0x0F8>(hq);

    if (st) outp[(size_t)t * (BATCH * NQ)] = hq;

    xw_cur = xw_n1;
    xw_n1  = xw_n2;
  }
  if (st) {
    out[(size_t)S_STEPS * BATCH * NQ + b * NQ + i] = hq;                 // h_n
    out[(size_t)S_STEPS * BATCH * NQ + BATCH * NQ + b * NQ + i] = c;     // c_n
  }
}

extern "C" void kernel_launch(void* const* d_in, const int* in_sizes, int n_in,
                              void* d_out, int out_size, void* d_ws, size_t ws_size,
                              hipStream_t stream) {
  const float* x  = (const float*)d_in[0];
  const float* Wf = (const float*)d_in[1];
  const float* bf = (const float*)d_in[2];
  const float* Wi = (const float*)d_in[3];
  const float* bi = (const float*)d_in[4];
  const float* Wu = (const float*)d_in[5];
  const float* bu = (const float*)d_in[6];
  const float* Wo = (const float*)d_in[7];
  const float* bo = (const float*)d_in[8];
  float* xw  = (float*)d_ws;               // (1024*128, 32) = 16.8 MB
  float* out = (float*)d_out;

  qlstm_pre<<<2048, 256, 0, stream>>>(x, Wf, bf, Wi, bi, Wu, bu, Wo, bo, xw);
  qlstm_seq<<<BATCH, 64, 0, stream>>>(xw, Wf, Wi, Wu, Wo, out);
}

// Round 3
// 520.284 us; speedup vs baseline: 1.5588x; 1.5588x over previous
//
#include <hip/hip_runtime.h>

#define S_STEPS 1024
#define BATCH 128
#define NQ 8

// ---- cross-lane helpers ------------------------------------------------
template<int OFF>
__device__ __forceinline__ float swzf(float x) {
  return __int_as_float(__builtin_amdgcn_ds_swizzle(__float_as_int(x), OFF));
}
__device__ __forceinline__ float tanh01(float x) {   // x in [0,1], no clamp
  float e = __builtin_amdgcn_exp2f(x * 2.88539008f); // e^{2x}
  return (e - 1.f) * __builtin_amdgcn_rcpf(e + 1.f);
}
__device__ __forceinline__ float tanh_c(float x) {
  x = fminf(fmaxf(x, -15.f), 15.f);
  float e = __builtin_amdgcn_exp2f(x * 2.88539008f); // e^{2x}
  return (e - 1.f) * __builtin_amdgcn_rcpf(e + 1.f);
}

// ---- kernel 1: xw[((b*32)+c)*1024 + t] = bias_c + x[t,b,:]·W_{g(c)}[q(c),:256]
// block: 256 thr, tile = 8 t × 4 b (32 x-rows), grid 128*32 = 4096
__global__ __launch_bounds__(256) void qlstm_pre(
    const float* __restrict__ x,
    const float* __restrict__ Wf, const float* __restrict__ bf,
    const float* __restrict__ Wi, const float* __restrict__ bi,
    const float* __restrict__ Wu, const float* __restrict__ bu,
    const float* __restrict__ Wo, const float* __restrict__ bo,
    float* __restrict__ xw)
{
  __shared__ float xs[32][260];            // lr = lt*4+lb ; pad keeps 16B align
  __shared__ float wsT[256][32];           // [j][c] : col-indexed -> bank = c
  const int tid = threadIdx.x;
  const int t0  = (blockIdx.x >> 5) * 8;
  const int b0  = (blockIdx.x & 31) * 4;

  // stage W transposed (LDS writes conflict-free; global side is L2-cached)
  for (int idx = tid; idx < 8192; idx += 256) {
    int c = idx & 31, j = idx >> 5;
    const float* Wg = (c < 8) ? Wf : (c < 16) ? Wi : (c < 24) ? Wu : Wo;
    wsT[j][c] = Wg[(c & 7) * 264 + j];
  }
  // stage x tile: 32 rows x 64 float4, coalesced
#pragma unroll
  for (int w = 0; w < 8; ++w) {
    int idx = w * 256 + tid;
    int lr = idx >> 6, jc = idx & 63;
    int lt = lr >> 2, lb = lr & 3;
    float4 v = ((const float4*)x)[(size_t)((t0 + lt) * 128 + (b0 + lb)) * 64 + jc];
    *(float4*)&xs[lr][jc * 4] = v;
  }
  __syncthreads();

  const int c  = tid & 31;
  const int rg = tid >> 5;                 // 0..7
  const int lb = rg >> 1;                  // 0..3  (batch within tile)
  const int th = rg & 1;                   // 0..1  (t half)
  const int g  = c >> 3, q = c & 7;
  const float* bias = (g == 0) ? bf : (g == 1) ? bi : (g == 2) ? bu : bo;
  float bv = bias[q];
  float acc[4];
#pragma unroll
  for (int k = 0; k < 4; ++k) acc[k] = bv;

  for (int jb = 0; jb < 64; ++jb) {
    float w0 = wsT[jb * 4 + 0][c];
    float w1 = wsT[jb * 4 + 1][c];
    float w2 = wsT[jb * 4 + 2][c];
    float w3 = wsT[jb * 4 + 3][c];
#pragma unroll
    for (int k = 0; k < 4; ++k) {
      int lr = (th * 4 + k) * 4 + lb;      // lt = th*4+k
      float4 xv = *(const float4*)&xs[lr][jb * 4];   // half-wave broadcast
      acc[k] = fmaf(xv.x, w0, acc[k]);
      acc[k] = fmaf(xv.y, w1, acc[k]);
      acc[k] = fmaf(xv.z, w2, acc[k]);
      acc[k] = fmaf(xv.w, w3, acc[k]);
    }
  }
  float4 o = make_float4(acc[0], acc[1], acc[2], acc[3]);
  *(float4*)&xw[(size_t)((b0 + lb) * 32 + c) * 1024 + t0 + th * 4] = o;
}

// ---- kernel 2: sequential recurrence, one wave per batch element -------
// lane = g*8+i. p(i) ~ f0(B7) f1(B7) f5(B5) f6(B6^B5) f7(B7^B6), f = cos^2 or 1-cos^2.
// Sum over i factorizes: all lanes of a group share the same 5 cos^2 values,
// so s = C0C1*T0 + S0S1*T1 computes locally (no DPP reduction).
__global__ __launch_bounds__(64) void qlstm_seq(
    const float* __restrict__ xw,
    const float* __restrict__ Wf, const float* __restrict__ Wi,
    const float* __restrict__ Wu, const float* __restrict__ Wo,
    float* __restrict__ out)
{
  const int b    = blockIdx.x;
  const int lane = threadIdx.x;
  const int g    = (lane >> 3) & 3;
  const int i    = lane & 7;
  const int B5 = (i >> 2) & 1, B6 = (i >> 1) & 1, B7 = i & 1;
  const bool M0 = B7, M5 = B5, M6 = (B6 ^ B5), M7 = (B7 ^ B6);

  const float* Wg = (g == 0) ? Wf : (g == 1) ? Wi : (g == 2) ? Wu : Wo;
  float wh[8];
#pragma unroll
  for (int j = 0; j < 8; ++j) wh[j] = Wg[i * 264 + 256 + j];

  float h[8];
#pragma unroll
  for (int j = 0; j < 8; ++j) h[j] = 0.f;
  float c = 0.f, hq = 0.f;

  const float* xwb = xw + ((size_t)b * 32 + (lane & 31)) * 1024;
  float4 cur = *(const float4*)(xwb + 0);
  float4 nxt = *(const float4*)(xwb + 4);

  float* outp = out + (size_t)b * NQ + i;
  const bool st = (lane < 8);

#pragma unroll 1
  for (int T = 0; T < S_STEPS; T += 4) {
    int tp = T + 8; tp = (tp > 1020) ? 1020 : tp;
    float4 nn = *(const float4*)(xwb + tp);
    float xv4[4] = {cur.x, cur.y, cur.z, cur.w};
#pragma unroll
    for (int u = 0; u < 4; ++u) {
      // param = xw + wh·h  (tree)
      float d0 = fmaf(wh[1], h[1], wh[0] * h[0]);
      float d1 = fmaf(wh[3], h[3], wh[2] * h[2]);
      float d2 = fmaf(wh[5], h[5], wh[4] * h[4]);
      float d3 = fmaf(wh[7], h[7], wh[6] * h[6]);
      float param = ((d0 + d1) + (d2 + d3)) + xv4[u];
      float cc = fmaf(0.5f, __builtin_amdgcn_cosf(param * 0.15915494f), 0.5f);

      // phase A: gather the 5 shared cos^2 of own gate group
      float C0 = swzf<0x018>(cc);
      float C1 = swzf<0x038>(cc);
      float C5 = swzf<0x0B8>(cc);
      float C6 = swzf<0x0D8>(cc);
      float C7 = swzf<0x0F8>(cc);
      float S0 = 1.f - C0, S1 = 1.f - C1;
      float S5 = 1.f - C5, S6 = 1.f - C6, S7 = 1.f - C7;

      // own numerator
      float f0 = M0 ? S0 : C0;
      float f1 = M0 ? S1 : C1;
      float f5 = M5 ? S5 : C5;
      float f6 = M6 ? S6 : C6;
      float f7 = M7 ? S7 : C7;
      float p  = ((f0 * f1) * (f5 * f6)) * f7;

      // analytic group sum (identical in every lane of the group)
      float U0 = fmaf(C5, C6, S5 * S6);
      float U1 = fmaf(C5, S6, S5 * C6);
      float T0 = fmaf(C7, U0, S7 * U1);
      float T1 = fmaf(S7, U0, C7 * U1);
      float s  = fmaf(C0 * C1, T0, (S0 * S1) * T1);
      float pn = p * __builtin_amdgcn_rcpf(s);

      // phase C: gather f,i,u,o for own index from the 4 gate groups
      float fv = swzf<0x007>(pn);
      float iv = swzf<0x107>(pn);
      float uv = swzf<0x207>(pn);
      float ov = swzf<0x307>(pn);

      float gv = tanh01(uv);
      c  = fmaf(fv, c, iv * gv);
      hq = ov * tanh_c(c);

      // phase D: broadcast h[0..7]
      h[0] = swzf<0x018>(hq);
      h[1] = swzf<0x038>(hq);
      h[2] = swzf<0x058>(hq);
      h[3] = swzf<0x078>(hq);
      h[4] = swzf<0x098>(hq);
      h[5] = swzf<0x0B8>(hq);
      h[6] = swzf<0x0D8>(hq);
      h[7] = swzf<0x0F8>(hq);

      if (st) outp[(size_t)(T + u) * (BATCH * NQ)] = hq;
    }
    cur = nxt;
    nxt = nn;
  }
  if (st) {
    out[(size_t)S_STEPS * BATCH * NQ + b * NQ + i] = hq;               // h_n
    out[(size_t)S_STEPS * BATCH * NQ + BATCH * NQ + b * NQ + i] = c;   // c_n
  }
}

extern "C" void kernel_launch(void* const* d_in, const int* in_sizes, int n_in,
                              void* d_out, int out_size, void* d_ws, size_t ws_size,
                              hipStream_t stream) {
  const float* x  = (const float*)d_in[0];
  const float* Wf = (const float*)d_in[1];
  const float* bf = (const float*)d_in[2];
  const float* Wi = (const float*)d_in[3];
  const float* bi = (const float*)d_in[4];
  const float* Wu = (const float*)d_in[5];
  const float* bu = (const float*)d_in[6];
  const float* Wo = (const float*)d_in[7];
  const float* bo = (const float*)d_in[8];
  float* xw  = (float*)d_ws;               // (128*32, 1024) floats = 16.8 MB
  float* out = (float*)d_out;

  qlstm_pre<<<4096, 256, 0, stream>>>(x, Wf, bf, Wi, bi, Wu, bu, Wo, bo, xw);
  qlstm_seq<<<BATCH, 64, 0, stream>>>(xw, Wf, Wi, Wu, Wo, out);
}

// Round 4
// 504.398 us; speedup vs baseline: 1.6079x; 1.0315x over previous
//
#include <hip/hip_runtime.h>

#define S_STEPS 1024
#define BATCH 128
#define NQ 8

using v2f = float __attribute__((ext_vector_type(2)));

// ---- cross-lane helpers ------------------------------------------------
template<int OFF>
__device__ __forceinline__ float swzf(float x) {
  return __int_as_float(__builtin_amdgcn_ds_swizzle(__float_as_int(x), OFF));
}
template<int CTRL>
__device__ __forceinline__ float qpf(float x) {   // quad_perm DPP
  return __int_as_float(__builtin_amdgcn_update_dpp(
      0, __float_as_int(x), CTRL, 0xf, 0xf, true));
}
template<int CTRL>
__device__ __forceinline__ int qpi(int x) {
  return __builtin_amdgcn_update_dpp(0, x, CTRL, 0xf, 0xf, true);
}

// ---- kernel 1: xw[((b*32)+c)*1024 + t] = bias_c + x[t,b,:]·W_{g(c)}[q(c),:256]
// 256 blocks x 256 thr; block tile 32t x 16b (512 rows); thread: 8 rows x 8 cols.
// W in LDS (XOR-swizzled, conflict-free); x read directly from global (L2).
__global__ __launch_bounds__(256) void qlstm_pre(
    const float* __restrict__ x,
    const float* __restrict__ Wf, const float* __restrict__ bf,
    const float* __restrict__ Wi, const float* __restrict__ bi,
    const float* __restrict__ Wu, const float* __restrict__ bu,
    const float* __restrict__ Wo, const float* __restrict__ bo,
    float* __restrict__ xw)
{
  __shared__ float ws[32 * 256];
  __shared__ float bsm[32];
  const int tid = threadIdx.x;

  // stage W with j4 ^= (c>>3)&3 swizzle (reads: 4 col-groups -> disjoint bank quads)
  for (int idx = tid; idx < 8192; idx += 256) {
    int c = idx >> 8, j = idx & 255;
    const float* Wg = (c < 8) ? Wf : (c < 16) ? Wi : (c < 24) ? Wu : Wo;
    float v = Wg[(c & 7) * 264 + j];
    ws[c * 256 + ((((j >> 2) ^ ((c >> 3) & 3)) << 2) | (j & 3))] = v;
  }
  if (tid < 32) {
    const float* bg = (tid < 8) ? bf : (tid < 16) ? bi : (tid < 24) ? bu : bo;
    bsm[tid] = bg[tid & 7];
  }
  __syncthreads();

  const int cg = tid & 3;          // col group: cols cg*8 .. cg*8+7
  const int rg = tid >> 2;         // row group: block-rows rg*8 .. rg*8+7
  const int t0 = (blockIdx.x >> 3) * 32;
  const int b0 = (blockIdx.x & 7) * 16;
  const int c0 = cg * 8;

  const float4* xp[8];
  int tis[8], bis[8];
#pragma unroll
  for (int k = 0; k < 8; ++k) {
    int br = rg * 8 + k;
    tis[k] = br >> 4; bis[k] = br & 15;
    xp[k] = (const float4*)(x + (size_t)((t0 + tis[k]) * 128 + (b0 + bis[k])) * 256);
  }

  float acc[8][8];
#pragma unroll
  for (int k = 0; k < 8; ++k)
#pragma unroll
    for (int cc = 0; cc < 8; ++cc) acc[k][cc] = bsm[c0 + cc];

  float4 xk[8];
#pragma unroll
  for (int k = 0; k < 8; ++k) xk[k] = xp[k][0];

  for (int j4 = 0; j4 < 64; ++j4) {
    int jn = (j4 < 63) ? j4 + 1 : 63;
    float4 xn[8];
#pragma unroll
    for (int k = 0; k < 8; ++k) xn[k] = xp[k][jn];

    float4 wv[8];
#pragma unroll
    for (int cc = 0; cc < 8; ++cc)
      wv[cc] = *(const float4*)&ws[(c0 + cc) * 256 + ((j4 ^ cg) << 2)];

#pragma unroll
    for (int k = 0; k < 8; ++k)
#pragma unroll
      for (int cc = 0; cc < 8; ++cc) {
        acc[k][cc] = fmaf(xk[k].x, wv[cc].x, acc[k][cc]);
        acc[k][cc] = fmaf(xk[k].y, wv[cc].y, acc[k][cc]);
        acc[k][cc] = fmaf(xk[k].z, wv[cc].z, acc[k][cc]);
        acc[k][cc] = fmaf(xk[k].w, wv[cc].w, acc[k][cc]);
      }
#pragma unroll
    for (int k = 0; k < 8; ++k) xk[k] = xn[k];
  }

#pragma unroll
  for (int k = 0; k < 8; ++k)
#pragma unroll
    for (int cc = 0; cc < 8; ++cc)
      xw[(size_t)((b0 + bis[k]) * 32 + c0 + cc) * 1024 + t0 + tis[k]] = acc[k][cc];
}

// ---- kernel 2: recurrence. 64 blocks x 64 thr; 2 batches/wave, 32 lanes/batch.
// lane: q=lane&31, i=q>>2 (prob index), g=q&3 (gate). Each lane computes its
// gate's 5 wire-params locally (dots+cos are i-independent -> replicated, off
// the latency chain). Cross-gate gather = quad_perm DPP; h all-gather = the
// single ds_swizzle phase per step.
__global__ __launch_bounds__(64) void qlstm_seq(
    const float* __restrict__ xw,
    const float* __restrict__ Wf, const float* __restrict__ Wi,
    const float* __restrict__ Wu, const float* __restrict__ Wo,
    float* __restrict__ out)
{
  const int lane = threadIdx.x;
  const int q = lane & 31;
  const int i = q >> 2;
  const int g = q & 3;
  const int b = blockIdx.x * 2 + (lane >> 5);
  const int B5 = (i >> 2) & 1, B6 = (i >> 1) & 1, B7 = i & 1;
  const int wires[5] = {0, 1, 5, 6, 7};
  const int M[5] = {B7, B7, B5, B6 ^ B5, B7 ^ B6};

  const float* Wg = (g == 0) ? Wf : (g == 1) ? Wi : (g == 2) ? Wu : Wo;

  v2f wh2[5][4];
  float sgn[5], off[5];
  const float* xp[5];
#pragma unroll
  for (int w = 0; w < 5; ++w) {
    const float* row = Wg + wires[w] * 264 + 256;
#pragma unroll
    for (int j2 = 0; j2 < 4; ++j2) {
      v2f t; t.x = row[j2 * 2]; t.y = row[j2 * 2 + 1];
      wh2[w][j2] = t;
    }
    sgn[w] = M[w] ? -1.f : 1.f;
    off[w] = M[w] ? 1.f : 0.f;
    xp[w] = xw + (size_t)(b * 32 + g * 8 + wires[w]) * 1024;
  }

  // probe quad_perm rotation direction (convention-proof gate selection)
  const int pr1 = qpi<0x39>(g);
  const int pr2 = qpi<0x4E>(g);
  const int pr3 = qpi<0x93>(g);

  v2f h2[4];
#pragma unroll
  for (int k = 0; k < 4; ++k) h2[k] = 0.f;
  float c = 0.f, hq = 0.f;

  float4 cur[5], nxt[5];
#pragma unroll
  for (int w = 0; w < 5; ++w) {
    cur[w] = *(const float4*)(xp[w] + 0);
    nxt[w] = *(const float4*)(xp[w] + 4);
  }

  const bool st = (g == 0);
  float* outp = out + (size_t)b * NQ + i;

#pragma unroll 1
  for (int T = 0; T < S_STEPS; T += 4) {
    int tp = T + 8; tp = (tp > 1020) ? 1020 : tp;
    float4 nn[5];
#pragma unroll
    for (int w = 0; w < 5; ++w) nn[w] = *(const float4*)(xp[w] + tp);

#pragma unroll
    for (int u = 0; u < 4; ++u) {
      // 5 local dots (packed) + cos^2
      float ccv[5];
#pragma unroll
      for (int w = 0; w < 5; ++w) {
        v2f a = wh2[w][0] * h2[0];
        a = wh2[w][1] * h2[1] + a;
        a = wh2[w][2] * h2[2] + a;
        a = wh2[w][3] * h2[3] + a;
        float param = (((const float*)&cur[w])[u] + a.x) + a.y;
        ccv[w] = fmaf(0.5f, __builtin_amdgcn_cosf(param * 0.15915494f), 0.5f);
      }
      float C0 = ccv[0], C1 = ccv[1], C5 = ccv[2], C6 = ccv[3], C7 = ccv[4];
      float S5 = 1.f - C5, S6 = 1.f - C6, S7 = 1.f - C7;

      float f0 = fmaf(sgn[0], C0, off[0]);
      float f1 = fmaf(sgn[1], C1, off[1]);
      float f5 = fmaf(sgn[2], C5, off[2]);
      float f6 = fmaf(sgn[3], C6, off[3]);
      float f7 = fmaf(sgn[4], C7, off[4]);
      float p  = ((f0 * f1) * (f5 * f6)) * f7;

      float P01 = C0 * C1;
      float Q01 = P01 + 1.f - (C0 + C1);   // S0*S1
      float U0 = fmaf(C5, C6, S5 * S6);
      float U1 = fmaf(C5, S6, S5 * C6);
      float T0 = fmaf(C7, U0, S7 * U1);
      float T1 = fmaf(S7, U0, C7 * U1);
      float s  = fmaf(P01, T0, Q01 * T1);
      float pn = p * __builtin_amdgcn_rcpf(s);

      // cross-gate gather within quad
      float r1 = qpf<0x39>(pn);
      float r2 = qpf<0x4E>(pn);
      float r3 = qpf<0x93>(pn);
      float fv = (g == 0) ? pn : (pr1 == 0) ? r1 : (pr2 == 0) ? r2 : r3;
      float iv = (g == 1) ? pn : (pr1 == 1) ? r1 : (pr2 == 1) ? r2 : r3;
      float uv = (g == 2) ? pn : (pr1 == 2) ? r1 : (pr2 == 2) ? r2 : r3;
      float ov = (g == 3) ? pn : (pr1 == 3) ? r1 : (pr2 == 3) ? r2 : r3;

      // tanh(uv), uv in [0,1]: Pade(3,2), |err| <= 3e-4
      float t2 = uv * uv;
      float gv = uv * (t2 + 15.f) * __builtin_amdgcn_rcpf(fmaf(6.f, t2, 15.f));
      c = fmaf(fv, c, iv * gv);
      float cl = fminf(fmaxf(c, -15.f), 15.f);
      float e = __builtin_amdgcn_exp2f(cl * 2.88539008f);   // e^{2c}
      float th = (e - 1.f) * __builtin_amdgcn_rcpf(e + 1.f);
      hq = ov * th;

      // h all-gather (single DS phase): src lane = (lane&3) | (j<<2)
      h2[0].x = swzf<0x003>(hq); h2[0].y = swzf<0x083>(hq);
      h2[1].x = swzf<0x103>(hq); h2[1].y = swzf<0x183>(hq);
      h2[2].x = swzf<0x203>(hq); h2[2].y = swzf<0x283>(hq);
      h2[3].x = swzf<0x303>(hq); h2[3].y = swzf<0x383>(hq);

      if (st) outp[(size_t)(T + u) * (BATCH * NQ)] = hq;
    }
#pragma unroll
    for (int w = 0; w < 5; ++w) { cur[w] = nxt[w]; nxt[w] = nn[w]; }
  }
  if (st) {
    out[(size_t)S_STEPS * BATCH * NQ + b * NQ + i] = hq;               // h_n
    out[(size_t)S_STEPS * BATCH * NQ + BATCH * NQ + b * NQ + i] = c;   // c_n
  }
}

extern "C" void kernel_launch(void* const* d_in, const int* in_sizes, int n_in,
                              void* d_out, int out_size, void* d_ws, size_t ws_size,
                              hipStream_t stream) {
  const float* x  = (const float*)d_in[0];
  const float* Wf = (const float*)d_in[1];
  const float* bf = (const float*)d_in[2];
  const float* Wi = (const float*)d_in[3];
  const float* bi = (const float*)d_in[4];
  const float* Wu = (const float*)d_in[5];
  const float* bu = (const float*)d_in[6];
  const float* Wo = (const float*)d_in[7];
  const float* bo = (const float*)d_in[8];
  float* xw  = (float*)d_ws;               // (128*32, 1024) floats = 16.8 MB
  float* out = (float*)d_out;

  qlstm_pre<<<256, 256, 0, stream>>>(x, Wf, bf, Wi, bi, Wu, bu, Wo, bo, xw);
  qlstm_seq<<<64, 64, 0, stream>>>(xw, Wf, Wi, Wu, Wo, out);
}